// Round 7
// baseline (2457.786 us; speedup 1.0000x reference)
//
#include <hip/hip_runtime.h>
#include <math.h>

#define DD 64

__device__ __forceinline__ float silu_f(float x) {
    return x / (1.0f + __expf(-x));
}

__device__ __forceinline__ unsigned f32_to_bf16_rne(float x) {
    unsigned u = __float_as_uint(x);
    unsigned r = ((u >> 16) & 1u) + 0x7fffu;
    return (u + r) >> 16;
}

__device__ __forceinline__ float2 bf2_lo_hi(unsigned u) {
    return make_float2(__uint_as_float(u << 16), __uint_as_float(u & 0xffff0000u));
}

__device__ __forceinline__ void gload_lds4(const float* gsrc, float* lds_base) {
    __builtin_amdgcn_global_load_lds(
        (const __attribute__((address_space(1))) void*)gsrc,
        (__attribute__((address_space(3))) void*)lds_base,
        4, 0, 0);
}

// ---------------- sort machinery ----------------
__global__ __launch_bounds__(256) void zero_kernel(int* p, int n) {
    int i = blockIdx.x * 256 + threadIdx.x;
    if (i < n) p[i] = 0;
}

__global__ __launch_bounds__(256) void hist_kernel(const int* __restrict__ eidx,
                                                   int* __restrict__ counts, int E) {
    int i = blockIdx.x * 256 + threadIdx.x;
    if (i < E) atomicAdd(&counts[((const int2*)eidx)[i].x], 1);
}

// single block, 1024 threads: exclusive scan of counts -> offs, cursor
__global__ __launch_bounds__(1024) void scan_kernel(const int* __restrict__ counts,
                                                    int* __restrict__ offs,
                                                    int* __restrict__ cursor, int N) {
    __shared__ int part[1024];
    int tid = threadIdx.x;
    int CH = (N + 1023) / 1024;
    int lo = tid * CH, hi = lo + CH; if (hi > N) hi = N; if (lo > N) lo = N;
    int s = 0;
    for (int i = lo; i < hi; ++i) s += counts[i];
    part[tid] = s;
    __syncthreads();
    for (int d = 1; d < 1024; d <<= 1) {
        int v = (tid >= d) ? part[tid - d] : 0;
        __syncthreads();
        part[tid] += v;
        __syncthreads();
    }
    int run = (tid == 0) ? 0 : part[tid - 1];
    for (int i = lo; i < hi; ++i) {
        offs[i] = run; cursor[i] = run;
        run += counts[i];
    }
}

__global__ __launch_bounds__(256) void scatter_kernel(const int* __restrict__ eidx,
                                                      int* __restrict__ cursor,
                                                      int* __restrict__ sorted, int E) {
    int i = blockIdx.x * 256 + threadIdx.x;
    if (i < E) {
        int p = atomicAdd(&cursor[((const int2*)eidx)[i].x], 1);
        sorted[p] = i;
    }
}

// ---------------- Kernel 1a: per-node A,B (scalar), C,D (chiral) + out1 init
__global__ __launch_bounds__(256) void node_transform_kernel(
    const float* __restrict__ ns, const float* __restrict__ nc,
    const float* __restrict__ Ws1, const float* __restrict__ Wc1,
    float* __restrict__ A, float* __restrict__ B,
    float* __restrict__ C, float* __restrict__ Dm,
    float* __restrict__ out1, int N)
{
    __shared__ float w1[128 * 64];
    __shared__ float wc1s[128 * 64];
    __shared__ float xs[4][2][64];
    __shared__ float ys[4][2][64];
    int tid = threadIdx.x;
    for (int i = tid; i < 128 * 64 / 4; i += 256) {
        ((float4*)w1)[i]   = ((const float4*)Ws1)[i];
        ((float4*)wc1s)[i] = ((const float4*)Wc1)[i];
    }
    __syncthreads();
    int wave = tid >> 6, lane = tid & 63;
    for (int nb = blockIdx.x * 8; nb < N; nb += gridDim.x * 8) {
        int n0 = nb + wave * 2;
        #pragma unroll
        for (int s = 0; s < 2; ++s) {
            int n = n0 + s;
            float xv = 0.f, yv = 0.f;
            if (n < N) { xv = ns[(size_t)n * DD + lane]; yv = nc[(size_t)n * DD + lane]; }
            xs[wave][s][lane] = xv;
            ys[wave][s][lane] = yv;
        }
        float aA[2] = {0.f, 0.f}, aB[2] = {0.f, 0.f}, aC[2] = {0.f, 0.f}, aD[2] = {0.f, 0.f};
        for (int k = 0; k < 64; ++k) {
            float wa  = w1[k * 64 + lane];
            float wb  = w1[(64 + k) * 64 + lane];
            float wca = wc1s[k * 64 + lane];
            float wcb = wc1s[(64 + k) * 64 + lane];
            #pragma unroll
            for (int s = 0; s < 2; ++s) {
                float xk = xs[wave][s][k];
                float yk = ys[wave][s][k];
                aA[s] += xk * wa;  aB[s] += xk * wb;
                aC[s] += yk * wca; aD[s] += yk * wcb;
            }
        }
        #pragma unroll
        for (int s = 0; s < 2; ++s) {
            int n = n0 + s;
            if (n < N) {
                A[(size_t)n * DD + lane]  = aA[s];
                B[(size_t)n * DD + lane]  = aB[s];
                C[(size_t)n * DD + lane]  = aC[s];
                Dm[(size_t)n * DD + lane] = aD[s];
                out1[(size_t)n * DD + lane] = ys[wave][s][lane];
            }
        }
    }
}

// ---------------- Kernel 1b: Vv norm -> out0 base only
__global__ __launch_bounds__(256) void node_vector_kernel(
    const float* __restrict__ ns, const float* __restrict__ nv,
    const float* __restrict__ WV, const float* __restrict__ bV,
    float* __restrict__ out0, int N)
{
    __shared__ float wv[64 * 64];
    __shared__ float vs[4][2][3][64];
    int tid = threadIdx.x;
    for (int i = tid; i < 64 * 64 / 4; i += 256)
        ((float4*)wv)[i] = ((const float4*)WV)[i];
    __syncthreads();
    int wave = tid >> 6, lane = tid & 63;
    float bVj = bV[lane];
    for (int nb = blockIdx.x * 8; nb < N; nb += gridDim.x * 8) {
        int n0 = nb + wave * 2;
        #pragma unroll
        for (int s = 0; s < 2; ++s) {
            int n = n0 + s;
            float v0 = 0.f, v1 = 0.f, v2 = 0.f;
            if (n < N) {
                v0 = nv[((size_t)n * 3 + 0) * DD + lane];
                v1 = nv[((size_t)n * 3 + 1) * DD + lane];
                v2 = nv[((size_t)n * 3 + 2) * DD + lane];
            }
            vs[wave][s][0][lane] = v0; vs[wave][s][1][lane] = v1; vs[wave][s][2][lane] = v2;
        }
        float a0[2], a1[2], a2[2];
        #pragma unroll
        for (int s = 0; s < 2; ++s) { a0[s] = bVj; a1[s] = bVj; a2[s] = bVj; }
        for (int k = 0; k < 64; ++k) {
            float w = wv[k * 64 + lane];
            #pragma unroll
            for (int s = 0; s < 2; ++s) {
                a0[s] += vs[wave][s][0][k] * w;
                a1[s] += vs[wave][s][1][k] * w;
                a2[s] += vs[wave][s][2][k] * w;
            }
        }
        #pragma unroll
        for (int s = 0; s < 2; ++s) {
            int n = n0 + s;
            if (n < N) {
                float norm = sqrtf(a0[s] * a0[s] + a1[s] * a1[s] + a2[s] * a2[s]);
                float x = ns[(size_t)n * DD + lane];
                out0[(size_t)n * DD + lane] = x * (1.f + norm);
            }
        }
    }
}

// ---------------- Kernel 2: edges — destination-sorted segments, ZERO atomics
#define SEPW 4
__global__ __launch_bounds__(256) void edge_segment_kernel(
    const float* __restrict__ A, const float* __restrict__ B,
    const float* __restrict__ nv, const float* __restrict__ pos,
    const int* __restrict__ eidx, const int* __restrict__ sorted,
    const int* __restrict__ offs, const int* __restrict__ counts,
    const float* __restrict__ bs1, const float* __restrict__ Ws2, const float* __restrict__ bs2,
    float* __restrict__ out0, float* __restrict__ out2, int N)
{
    __shared__ unsigned w2p[32 * 192];       // 24 KiB bf16-packed Ws2
    __shared__ float stB[4][SEPW][64];       //  4 KiB (B-row, overwritten with h)
    __shared__ float stV[4][SEPW][3][64];    // 12 KiB
    int tid = threadIdx.x;
    for (int i = tid; i < 32 * 192; i += 256) {
        int kp = i / 192, c = i % 192;
        float a = Ws2[(size_t)(2 * kp) * 192 + c];
        float b = Ws2[(size_t)(2 * kp + 1) * 192 + c];
        w2p[i] = f32_to_bf16_rne(a) | (f32_to_bf16_rne(b) << 16);
    }
    __syncthreads();
    int wave = __builtin_amdgcn_readfirstlane(tid >> 6);
    int lane = tid & 63;
    float b1  = bs1[lane];
    float b2v = bs2[lane], b2e = bs2[64 + lane], b2s = bs2[128 + lane];

    for (int n = __builtin_amdgcn_readfirstlane(blockIdx.x * 4 + wave); n < N;
         n += __builtin_amdgcn_readfirstlane(gridDim.x * 4)) {
        int base = __builtin_amdgcn_readfirstlane(offs[n]);
        int cnt  = __builtin_amdgcn_readfirstlane(counts[n]);
        float a  = A[(size_t)n * DD + lane];
        float o0 = out0[(size_t)n * DD + lane];
        float acc0 = nv[((size_t)n * 3 + 0) * DD + lane];
        float acc1 = nv[((size_t)n * 3 + 1) * DD + lane];
        float acc2 = nv[((size_t)n * 3 + 2) * DD + lane];
        float ssacc = 0.f;
        float pnx = pos[(size_t)n * 3 + 0], pny = pos[(size_t)n * 3 + 1], pnz = pos[(size_t)n * 3 + 2];

        for (int c0 = 0; c0 < cnt; c0 += SEPW) {
            int m = cnt - c0; if (m > SEPW) m = SEPW;
            int i1a[SEPW];
            #pragma unroll
            for (int e = 0; e < SEPW; ++e) {
                int i1 = 0;
                if (e < m) {
                    int eid = sorted[base + c0 + e];
                    i1 = eidx[2 * (size_t)eid + 1];
                }
                i1a[e] = __builtin_amdgcn_readfirstlane(i1);
            }
            #pragma unroll
            for (int e = 0; e < SEPW; ++e) {
                if (e < m) {
                    gload_lds4(B + (size_t)i1a[e] * DD + lane, &stB[wave][e][0]);
                    gload_lds4(nv + ((size_t)i1a[e] * 3 + 0) * DD + lane, &stV[wave][e][0][0]);
                    gload_lds4(nv + ((size_t)i1a[e] * 3 + 1) * DD + lane, &stV[wave][e][1][0]);
                    gload_lds4(nv + ((size_t)i1a[e] * 3 + 2) * DD + lane, &stV[wave][e][2][0]);
                }
            }
            asm volatile("s_waitcnt vmcnt(0)" ::: "memory");
            // h in place over stB (stale slots e>=m produce garbage we never use)
            #pragma unroll
            for (int e = 0; e < SEPW; ++e) {
                if (e < m) {
                    float h = silu_f(a + stB[wave][e][lane] + b1);
                    stB[wave][e][lane] = h;
                }
            }
            float agv[SEPW], age[SEPW], ass[SEPW];
            #pragma unroll
            for (int e = 0; e < SEPW; ++e) { agv[e] = 0.f; age[e] = 0.f; ass[e] = 0.f; }
            for (int k4 = 0; k4 < 64; k4 += 4) {
                float4 hk[SEPW];
                #pragma unroll
                for (int e = 0; e < SEPW; ++e) hk[e] = *(const float4*)&stB[wave][e][k4];
                int kp = k4 >> 1;
                float2 w0a = bf2_lo_hi(w2p[kp * 192 + lane]);
                float2 w0b = bf2_lo_hi(w2p[(kp + 1) * 192 + lane]);
                float2 w1a = bf2_lo_hi(w2p[kp * 192 + 64 + lane]);
                float2 w1b = bf2_lo_hi(w2p[(kp + 1) * 192 + 64 + lane]);
                float2 w2a = bf2_lo_hi(w2p[kp * 192 + 128 + lane]);
                float2 w2b = bf2_lo_hi(w2p[(kp + 1) * 192 + 128 + lane]);
                #pragma unroll
                for (int e = 0; e < SEPW; ++e) {
                    agv[e] += hk[e].x * w0a.x + hk[e].y * w0a.y + hk[e].z * w0b.x + hk[e].w * w0b.y;
                    age[e] += hk[e].x * w1a.x + hk[e].y * w1a.y + hk[e].z * w1b.x + hk[e].w * w1b.y;
                    ass[e] += hk[e].x * w2a.x + hk[e].y * w2a.y + hk[e].z * w2b.x + hk[e].w * w2b.y;
                }
            }
            #pragma unroll
            for (int e = 0; e < SEPW; ++e) {
                if (e < m) {
                    int i1 = i1a[e];
                    float gv = agv[e] + b2v, ge = age[e] + b2e;
                    ssacc += ass[e] + b2s;
                    float rx = pos[(size_t)i1 * 3 + 0] - pnx;
                    float ry = pos[(size_t)i1 * 3 + 1] - pny;
                    float rz = pos[(size_t)i1 * 3 + 2] - pnz;
                    acc0 += gv * stV[wave][e][0][lane] + ge * rx;
                    acc1 += gv * stV[wave][e][1][lane] + ge * ry;
                    acc2 += gv * stV[wave][e][2][lane] + ge * rz;
                }
            }
        }
        out0[(size_t)n * DD + lane] = o0 + ssacc;
        out2[((size_t)n * 3 + 0) * DD + lane] = acc0;
        out2[((size_t)n * 3 + 1) * DD + lane] = acc1;
        out2[((size_t)n * 3 + 2) * DD + lane] = acc2;
    }
}

// ---------------- Kernel 3: triplets — round-6 version (async LDS staging, atomics)
#define TPW 4
__global__ __launch_bounds__(256) void triplet_kernel(
    const float* __restrict__ C, const float* __restrict__ Dm,
    const float* __restrict__ pos, const int* __restrict__ tidx,
    const float* __restrict__ bc1, const float* __restrict__ Wc2, const float* __restrict__ bc2,
    float* __restrict__ out1, int T)
{
    __shared__ float wT[64 * 64];
    __shared__ float stC[4][TPW][64];
    __shared__ float stD[4][TPW][3][64];
    int tid = threadIdx.x;
    for (int i = tid; i < 64 * 64 / 4; i += 256)
        ((float4*)wT)[i] = ((const float4*)Wc2)[i];
    __syncthreads();
    int wave = __builtin_amdgcn_readfirstlane(tid >> 6);
    int lane = tid & 63;
    float b1 = bc1[lane];
    float b2 = bc2[lane] * 3.0f;
    for (long bb = (long)blockIdx.x * (4 * TPW); bb < T; bb += (long)gridDim.x * (4 * TPW)) {
        long t0 = bb + wave * TPW;
        int ib[TPW], it1[TPW], it2[TPW], it3[TPW];
        #pragma unroll
        for (int e = 0; e < TPW; ++e) {
            long t = t0 + e;
            int b = 0, t1 = 0, t2 = 0, t3 = 0;
            if (t < T) { int4 q = ((const int4*)tidx)[t]; b = q.x; t1 = q.y; t2 = q.z; t3 = q.w; }
            ib[e]  = __builtin_amdgcn_readfirstlane(b);
            it1[e] = __builtin_amdgcn_readfirstlane(t1);
            it2[e] = __builtin_amdgcn_readfirstlane(t2);
            it3[e] = __builtin_amdgcn_readfirstlane(t3);
        }
        #pragma unroll
        for (int e = 0; e < TPW; ++e) {
            gload_lds4(C  + (size_t)ib[e]  * DD + lane, &stC[wave][e][0]);
            gload_lds4(Dm + (size_t)it1[e] * DD + lane, &stD[wave][e][0][0]);
            gload_lds4(Dm + (size_t)it2[e] * DD + lane, &stD[wave][e][1][0]);
            gload_lds4(Dm + (size_t)it3[e] * DD + lane, &stD[wave][e][2][0]);
        }
        asm volatile("s_waitcnt vmcnt(0)" ::: "memory");
        float inv[TPW];
        #pragma unroll
        for (int e = 0; e < TPW; ++e) {
            float hb = stC[wave][e][lane] + b1;
            float h = silu_f(hb + stD[wave][e][0][lane])
                    + silu_f(hb + stD[wave][e][1][lane])
                    + silu_f(hb + stD[wave][e][2][lane]);
            stC[wave][e][lane] = h;
            int b = ib[e], t1 = it1[e], t2 = it2[e], t3 = it3[e];
            double pbx = pos[(size_t)b * 3], pby = pos[(size_t)b * 3 + 1], pbz = pos[(size_t)b * 3 + 2];
            double r1x = pbx - pos[(size_t)t1 * 3], r1y = pby - pos[(size_t)t1 * 3 + 1], r1z = pbz - pos[(size_t)t1 * 3 + 2];
            double r2x = pbx - pos[(size_t)t2 * 3], r2y = pby - pos[(size_t)t2 * 3 + 1], r2z = pbz - pos[(size_t)t2 * 3 + 2];
            double r3x = pbx - pos[(size_t)t3 * 3], r3y = pby - pos[(size_t)t3 * 3 + 1], r3z = pbz - pos[(size_t)t3 * 3 + 2];
            double cx = r2y * r3z - r2z * r3y;
            double cy = r2z * r3x - r2x * r3z;
            double cz = r2x * r3y - r2y * r3x;
            double stp = r1x * cx + r1y * cy + r1z * cz;
            inv[e] = (float)(1.0 / (stp + 0.01));
        }
        float acc[TPW];
        #pragma unroll
        for (int e = 0; e < TPW; ++e) acc[e] = 0.f;
        for (int k4 = 0; k4 < 64; k4 += 4) {
            float4 hk[TPW];
            #pragma unroll
            for (int e = 0; e < TPW; ++e) hk[e] = *(const float4*)&stC[wave][e][k4];
            #pragma unroll
            for (int kk = 0; kk < 4; ++kk) {
                float wk = wT[(k4 + kk) * 64 + lane];
                #pragma unroll
                for (int e = 0; e < TPW; ++e) acc[e] += (&hk[e].x)[kk] * wk;
            }
        }
        #pragma unroll
        for (int e = 0; e < TPW; ++e) {
            long t = t0 + e;
            if (t >= T) break;
            unsafeAtomicAdd(&out1[(size_t)ib[e] * DD + lane], (acc[e] + b2) * inv[e]);
        }
    }
}

extern "C" void kernel_launch(void* const* d_in, const int* in_sizes, int n_in,
                              void* d_out, int out_size, void* d_ws, size_t ws_size,
                              hipStream_t stream)
{
    const float* ns  = (const float*)d_in[0];
    const float* nc  = (const float*)d_in[1];
    const float* nv  = (const float*)d_in[2];
    const float* pos = (const float*)d_in[3];
    const int* eidx  = (const int*)d_in[4];
    const int* tidx  = (const int*)d_in[5];
    const float* Ws1 = (const float*)d_in[6];
    const float* bs1 = (const float*)d_in[7];
    const float* Ws2 = (const float*)d_in[8];
    const float* bs2 = (const float*)d_in[9];
    const float* Wc1 = (const float*)d_in[10];
    const float* bc1 = (const float*)d_in[11];
    const float* Wc2 = (const float*)d_in[12];
    const float* bc2 = (const float*)d_in[13];
    const float* WV  = (const float*)d_in[14];
    const float* bV  = (const float*)d_in[15];

    int N = in_sizes[0] / 64;
    int E = in_sizes[4] / 2;
    int T = in_sizes[5] / 4;

    float* out0 = (float*)d_out;
    float* out1 = out0 + (size_t)N * 64;
    float* out2 = out1 + (size_t)N * 64;

    float* A  = (float*)d_ws;
    float* B  = A + (size_t)N * 64;
    float* C  = B + (size_t)N * 64;
    float* Dm = C + (size_t)N * 64;
    int* counts = (int*)(Dm + (size_t)N * 64);
    int* offs   = counts + N;
    int* cursor = offs + N;
    int* sorted = cursor + N;

    zero_kernel<<<(N + 255) / 256, 256, 0, stream>>>(counts, N);
    node_transform_kernel<<<2048, 256, 0, stream>>>(ns, nc, Ws1, Wc1, A, B, C, Dm, out1, N);
    node_vector_kernel<<<2048, 256, 0, stream>>>(ns, nv, WV, bV, out0, N);
    hist_kernel<<<(E + 255) / 256, 256, 0, stream>>>(eidx, counts, E);
    scan_kernel<<<1, 1024, 0, stream>>>(counts, offs, cursor, N);
    scatter_kernel<<<(E + 255) / 256, 256, 0, stream>>>(eidx, cursor, sorted, E);
    edge_segment_kernel<<<(N + 3) / 4, 256, 0, stream>>>(A, B, nv, pos, eidx, sorted, offs, counts,
                                                         bs1, Ws2, bs2, out0, out2, N);
    triplet_kernel<<<4096, 256, 0, stream>>>(C, Dm, pos, tidx, bc1, Wc2, bc2, out1, T);
}

// Round 8
// 1323.317 us; speedup vs baseline: 1.8573x; 1.8573x over previous
//
#include <hip/hip_runtime.h>
#include <math.h>

#define DD 64

__device__ __forceinline__ float silu_f(float x) {
    return x / (1.0f + __expf(-x));
}

__device__ __forceinline__ unsigned f32_to_bf16_rne(float x) {
    unsigned u = __float_as_uint(x);
    unsigned r = ((u >> 16) & 1u) + 0x7fffu;
    return (u + r) >> 16;
}

__device__ __forceinline__ float2 bf2_lo_hi(unsigned u) {
    return make_float2(__uint_as_float(u << 16), __uint_as_float(u & 0xffff0000u));
}

__device__ __forceinline__ void gload_lds4(const float* gsrc, float* lds_base) {
    __builtin_amdgcn_global_load_lds(
        (const __attribute__((address_space(1))) void*)gsrc,
        (__attribute__((address_space(3))) void*)lds_base,
        4, 0, 0);
}

#define RFL(x) __builtin_amdgcn_readfirstlane(x)

// ---------------- prep: rel[e] = pos[e1] - pos[e0]  ([E][3] floats)
__global__ __launch_bounds__(256) void rel_kernel(const int* __restrict__ eidx,
                                                  const float* __restrict__ pos,
                                                  float* __restrict__ rel, int E)
{
    int e = blockIdx.x * 256 + threadIdx.x;
    if (e < E) {
        int2 p = ((const int2*)eidx)[e];
        rel[3 * (size_t)e + 0] = pos[(size_t)p.y * 3 + 0] - pos[(size_t)p.x * 3 + 0];
        rel[3 * (size_t)e + 1] = pos[(size_t)p.y * 3 + 1] - pos[(size_t)p.x * 3 + 1];
        rel[3 * (size_t)e + 2] = pos[(size_t)p.y * 3 + 2] - pos[(size_t)p.x * 3 + 2];
    }
}

// ---------------- Kernel 1a: per-node A,B (scalar), C,D (chiral) + out1 init
__global__ __launch_bounds__(256) void node_transform_kernel(
    const float* __restrict__ ns, const float* __restrict__ nc,
    const float* __restrict__ Ws1, const float* __restrict__ Wc1,
    float* __restrict__ A, float* __restrict__ B,
    float* __restrict__ C, float* __restrict__ Dm,
    float* __restrict__ out1, int N)
{
    __shared__ float w1[128 * 64];
    __shared__ float wc1s[128 * 64];
    __shared__ float xs[4][2][64];
    __shared__ float ys[4][2][64];
    int tid = threadIdx.x;
    for (int i = tid; i < 128 * 64 / 4; i += 256) {
        ((float4*)w1)[i]   = ((const float4*)Ws1)[i];
        ((float4*)wc1s)[i] = ((const float4*)Wc1)[i];
    }
    __syncthreads();
    int wave = tid >> 6, lane = tid & 63;
    for (int nb = blockIdx.x * 8; nb < N; nb += gridDim.x * 8) {
        int n0 = nb + wave * 2;
        #pragma unroll
        for (int s = 0; s < 2; ++s) {
            int n = n0 + s;
            float xv = 0.f, yv = 0.f;
            if (n < N) { xv = ns[(size_t)n * DD + lane]; yv = nc[(size_t)n * DD + lane]; }
            xs[wave][s][lane] = xv;
            ys[wave][s][lane] = yv;
        }
        float aA[2] = {0.f, 0.f}, aB[2] = {0.f, 0.f}, aC[2] = {0.f, 0.f}, aD[2] = {0.f, 0.f};
        for (int k = 0; k < 64; ++k) {
            float wa  = w1[k * 64 + lane];
            float wb  = w1[(64 + k) * 64 + lane];
            float wca = wc1s[k * 64 + lane];
            float wcb = wc1s[(64 + k) * 64 + lane];
            #pragma unroll
            for (int s = 0; s < 2; ++s) {
                float xk = xs[wave][s][k];
                float yk = ys[wave][s][k];
                aA[s] += xk * wa;  aB[s] += xk * wb;
                aC[s] += yk * wca; aD[s] += yk * wcb;
            }
        }
        #pragma unroll
        for (int s = 0; s < 2; ++s) {
            int n = n0 + s;
            if (n < N) {
                A[(size_t)n * DD + lane]  = aA[s];
                B[(size_t)n * DD + lane]  = aB[s];
                C[(size_t)n * DD + lane]  = aC[s];
                Dm[(size_t)n * DD + lane] = aD[s];
                out1[(size_t)n * DD + lane] = ys[wave][s][lane];
            }
        }
    }
}

// ---------------- Kernel 1b: Vv norm -> out0 base, out2 base (nv copy)
__global__ __launch_bounds__(256) void node_vector_kernel(
    const float* __restrict__ ns, const float* __restrict__ nv,
    const float* __restrict__ WV, const float* __restrict__ bV,
    float* __restrict__ out0, float* __restrict__ out2, int N)
{
    __shared__ float wv[64 * 64];
    __shared__ float vs[4][2][3][64];
    int tid = threadIdx.x;
    for (int i = tid; i < 64 * 64 / 4; i += 256)
        ((float4*)wv)[i] = ((const float4*)WV)[i];
    __syncthreads();
    int wave = tid >> 6, lane = tid & 63;
    float bVj = bV[lane];
    for (int nb = blockIdx.x * 8; nb < N; nb += gridDim.x * 8) {
        int n0 = nb + wave * 2;
        #pragma unroll
        for (int s = 0; s < 2; ++s) {
            int n = n0 + s;
            float v0 = 0.f, v1 = 0.f, v2 = 0.f;
            if (n < N) {
                v0 = nv[((size_t)n * 3 + 0) * DD + lane];
                v1 = nv[((size_t)n * 3 + 1) * DD + lane];
                v2 = nv[((size_t)n * 3 + 2) * DD + lane];
            }
            vs[wave][s][0][lane] = v0; vs[wave][s][1][lane] = v1; vs[wave][s][2][lane] = v2;
        }
        float a0[2], a1[2], a2[2];
        #pragma unroll
        for (int s = 0; s < 2; ++s) { a0[s] = bVj; a1[s] = bVj; a2[s] = bVj; }
        for (int k = 0; k < 64; ++k) {
            float w = wv[k * 64 + lane];
            #pragma unroll
            for (int s = 0; s < 2; ++s) {
                a0[s] += vs[wave][s][0][k] * w;
                a1[s] += vs[wave][s][1][k] * w;
                a2[s] += vs[wave][s][2][k] * w;
            }
        }
        #pragma unroll
        for (int s = 0; s < 2; ++s) {
            int n = n0 + s;
            if (n < N) {
                float norm = sqrtf(a0[s] * a0[s] + a1[s] * a1[s] + a2[s] * a2[s]);
                float x = ns[(size_t)n * DD + lane];
                out0[(size_t)n * DD + lane] = x * (1.f + norm);
                out2[((size_t)n * 3 + 0) * DD + lane] = vs[wave][s][0][lane];
                out2[((size_t)n * 3 + 1) * DD + lane] = vs[wave][s][1][lane];
                out2[((size_t)n * 3 + 2) * DD + lane] = vs[wave][s][2][lane];
            }
        }
    }
}

// ---------------- Kernel 2: edges — LDS double-buffered pipeline, counted vmcnt
#define EPW 4

__device__ __forceinline__ void issue_group(
    const float* __restrict__ A, const float* __restrict__ B,
    const float* __restrict__ nv,
    const int* s0, const int* s1,
    float (*pA)[64], float (*pB)[64], float (*pV)[3][64], int lane)
{
    #pragma unroll
    for (int e = 0; e < EPW; ++e) {
        gload_lds4(A + ((unsigned)s0[e] * 64u + lane), &pA[e][0]);
        gload_lds4(B + ((unsigned)s1[e] * 64u + lane), &pB[e][0]);
        gload_lds4(nv + (((unsigned)s1[e] * 3u + 0) * 64u + lane), &pV[e][0][0]);
        gload_lds4(nv + (((unsigned)s1[e] * 3u + 1) * 64u + lane), &pV[e][1][0]);
        gload_lds4(nv + (((unsigned)s1[e] * 3u + 2) * 64u + lane), &pV[e][2][0]);
    }
}

__global__ __launch_bounds__(256) void edge_kernel(
    const float* __restrict__ A, const float* __restrict__ B,
    const float* __restrict__ nv, const float* __restrict__ rel,
    const int* __restrict__ eidx,
    const float* __restrict__ bs1, const float* __restrict__ Ws2, const float* __restrict__ bs2,
    float* __restrict__ out0, float* __restrict__ out2, int E)
{
    __shared__ unsigned w2p[32 * 192];        // 24 KiB bf16-packed Ws2
    __shared__ float stA[2][4][EPW][64];      //  8 KiB (A-row, overwritten with h)
    __shared__ float stB[2][4][EPW][64];      //  8 KiB
    __shared__ float stV[2][4][EPW][3][64];   // 24 KiB
    int tid = threadIdx.x;
    for (int i = tid; i < 32 * 192; i += 256) {
        int kp = i / 192, c = i % 192;
        float a = Ws2[(size_t)(2 * kp) * 192 + c];
        float b = Ws2[(size_t)(2 * kp + 1) * 192 + c];
        w2p[i] = f32_to_bf16_rne(a) | (f32_to_bf16_rne(b) << 16);
    }
    __syncthreads();
    int wave = RFL(tid >> 6);
    int lane = tid & 63;
    float b1  = bs1[lane];
    float b2v = bs2[lane], b2e = bs2[64 + lane], b2s = bs2[128 + lane];
    int zv; asm volatile("v_mov_b32 %0, 0" : "=v"(zv));  // opaque 0: forces VMEM (not SMEM) loads

    long stride = (long)gridDim.x * 16;
    long gP = (long)blockIdx.x * 16 + wave * 4;
    if (gP >= E) return;

    // prologue: idx(P) -> gathers(P) -> buf0; prefetch idx(Q), rel(P)
    int4 ia = *(const int4*)((const char*)eidx + gP * 8 + zv);
    int4 ib = *(const int4*)((const char*)eidx + gP * 8 + 16 + zv);
    int s0[EPW], s1[EPW];
    s0[0] = RFL(ia.x); s1[0] = RFL(ia.y); s0[1] = RFL(ia.z); s1[1] = RFL(ia.w);
    s0[2] = RFL(ib.x); s1[2] = RFL(ib.y); s0[3] = RFL(ib.z); s1[3] = RFL(ib.w);
    issue_group(A, B, nv, s0, s1, stA[0][wave], stB[0][wave], stV[0][wave], lane);
    {
        long gQ = gP + stride;
        long gQl = (gQ + 4 <= E) ? gQ : ((gQ < E) ? (long)E - 4 : gP);
        ia = *(const int4*)((const char*)eidx + gQl * 8 + zv);
        ib = *(const int4*)((const char*)eidx + gQl * 8 + 16 + zv);
    }
    float4 r0 = *(const float4*)((const char*)rel + gP * 12 + zv);
    float4 r1 = *(const float4*)((const char*)rel + gP * 12 + 16 + zv);
    float4 r2 = *(const float4*)((const char*)rel + gP * 12 + 32 + zv);

    int cur = 0;
    for (; gP < E; gP += stride, cur ^= 1) {
        long gQ = gP + stride;
        bool hasQ = (gQ < E);
        // next-group indices become usable (compiler inserts counted vmcnt for ia/ib here)
        int n0[EPW], n1[EPW];
        n0[0] = RFL(ia.x); n1[0] = RFL(ia.y); n0[1] = RFL(ia.z); n1[1] = RFL(ia.w);
        n0[2] = RFL(ib.x); n1[2] = RFL(ib.y); n0[3] = RFL(ib.z); n1[3] = RFL(ib.w);
        float4 q0 = r0, q1 = r1, q2 = r2;
        if (hasQ) {
            issue_group(A, B, nv, n0, n1, stA[cur ^ 1][wave], stB[cur ^ 1][wave], stV[cur ^ 1][wave], lane);
            long gQl = (gQ + 4 <= E) ? gQ : (long)E - 4;
            long gR  = gQ + stride;
            long gRl = (gR + 4 <= E) ? gR : gQl;
            ia = *(const int4*)((const char*)eidx + gRl * 8 + zv);
            ib = *(const int4*)((const char*)eidx + gRl * 8 + 16 + zv);
            q0 = *(const float4*)((const char*)rel + gQl * 12 + zv);
            q1 = *(const float4*)((const char*)rel + gQl * 12 + 16 + zv);
            q2 = *(const float4*)((const char*)rel + gQl * 12 + 32 + zv);
            // newer-than-gathers(P) ops: idxQ(2)+relP(3)+atomics(16)+gathersQ(20)+idxR(2)+relQ(3)=46
            asm volatile("s_waitcnt vmcnt(46)" ::: "memory");
        } else {
            asm volatile("s_waitcnt vmcnt(0)" ::: "memory");
        }
        __builtin_amdgcn_sched_barrier(0);
        // ---- h phase: in-place over stA[cur]
        #pragma unroll
        for (int e = 0; e < EPW; ++e) {
            float h = silu_f(stA[cur][wave][e][lane] + stB[cur][wave][e][lane] + b1);
            stA[cur][wave][e][lane] = h;
        }
        // ---- matvec h @ Ws2 (bf16 weights)
        float agv[EPW], age[EPW], ass[EPW];
        #pragma unroll
        for (int e = 0; e < EPW; ++e) { agv[e] = 0.f; age[e] = 0.f; ass[e] = 0.f; }
        for (int k4 = 0; k4 < 64; k4 += 4) {
            float4 hk[EPW];
            #pragma unroll
            for (int e = 0; e < EPW; ++e) hk[e] = *(const float4*)&stA[cur][wave][e][k4];
            int kp = k4 >> 1;
            float2 w0a = bf2_lo_hi(w2p[kp * 192 + lane]);
            float2 w0b = bf2_lo_hi(w2p[(kp + 1) * 192 + lane]);
            float2 w1a = bf2_lo_hi(w2p[kp * 192 + 64 + lane]);
            float2 w1b = bf2_lo_hi(w2p[(kp + 1) * 192 + 64 + lane]);
            float2 w2a = bf2_lo_hi(w2p[kp * 192 + 128 + lane]);
            float2 w2b = bf2_lo_hi(w2p[(kp + 1) * 192 + 128 + lane]);
            #pragma unroll
            for (int e = 0; e < EPW; ++e) {
                agv[e] += hk[e].x * w0a.x + hk[e].y * w0a.y + hk[e].z * w0b.x + hk[e].w * w0b.y;
                age[e] += hk[e].x * w1a.x + hk[e].y * w1a.y + hk[e].z * w1b.x + hk[e].w * w1b.y;
                ass[e] += hk[e].x * w2a.x + hk[e].y * w2a.y + hk[e].z * w2b.x + hk[e].w * w2b.y;
            }
        }
        // ---- scatter (rel from prefetched regs; V rows from LDS)
        float rx[EPW] = {r0.x, r0.w, r1.z, r2.y};
        float ry[EPW] = {r0.y, r1.x, r1.w, r2.z};
        float rz[EPW] = {r0.z, r1.y, r2.x, r2.w};
        #pragma unroll
        for (int e = 0; e < EPW; ++e) {
            long eid = gP + e;
            if (eid < E) {
                int i0 = s0[e];
                float gv = agv[e] + b2v, ge = age[e] + b2e;
                unsafeAtomicAdd(&out0[(unsigned)i0 * 64u + lane], ass[e] + b2s);
                unsafeAtomicAdd(&out2[((unsigned)i0 * 3u + 0) * 64u + lane],
                                gv * stV[cur][wave][e][0][lane] + ge * rx[e]);
                unsafeAtomicAdd(&out2[((unsigned)i0 * 3u + 1) * 64u + lane],
                                gv * stV[cur][wave][e][1][lane] + ge * ry[e]);
                unsafeAtomicAdd(&out2[((unsigned)i0 * 3u + 2) * 64u + lane],
                                gv * stV[cur][wave][e][2][lane] + ge * rz[e]);
            }
        }
        // ---- rotate
        #pragma unroll
        for (int e = 0; e < EPW; ++e) { s0[e] = n0[e]; s1[e] = n1[e]; }
        r0 = q0; r1 = q1; r2 = q2;
    }
}

// ---------------- Kernel 3: triplets — round-6 version (async LDS staging)
#define TPW 4
__global__ __launch_bounds__(256) void triplet_kernel(
    const float* __restrict__ C, const float* __restrict__ Dm,
    const float* __restrict__ pos, const int* __restrict__ tidx,
    const float* __restrict__ bc1, const float* __restrict__ Wc2, const float* __restrict__ bc2,
    float* __restrict__ out1, int T)
{
    __shared__ float wT[64 * 64];
    __shared__ float stC[4][TPW][64];
    __shared__ float stD[4][TPW][3][64];
    int tid = threadIdx.x;
    for (int i = tid; i < 64 * 64 / 4; i += 256)
        ((float4*)wT)[i] = ((const float4*)Wc2)[i];
    __syncthreads();
    int wave = RFL(tid >> 6);
    int lane = tid & 63;
    float b1 = bc1[lane];
    float b2 = bc2[lane] * 3.0f;
    for (long bb = (long)blockIdx.x * (4 * TPW); bb < T; bb += (long)gridDim.x * (4 * TPW)) {
        long t0 = bb + wave * TPW;
        int ib[TPW], it1[TPW], it2[TPW], it3[TPW];
        #pragma unroll
        for (int e = 0; e < TPW; ++e) {
            long t = t0 + e;
            int b = 0, t1 = 0, t2 = 0, t3 = 0;
            if (t < T) { int4 q = ((const int4*)tidx)[t]; b = q.x; t1 = q.y; t2 = q.z; t3 = q.w; }
            ib[e]  = RFL(b);
            it1[e] = RFL(t1);
            it2[e] = RFL(t2);
            it3[e] = RFL(t3);
        }
        #pragma unroll
        for (int e = 0; e < TPW; ++e) {
            gload_lds4(C  + (size_t)ib[e]  * DD + lane, &stC[wave][e][0]);
            gload_lds4(Dm + (size_t)it1[e] * DD + lane, &stD[wave][e][0][0]);
            gload_lds4(Dm + (size_t)it2[e] * DD + lane, &stD[wave][e][1][0]);
            gload_lds4(Dm + (size_t)it3[e] * DD + lane, &stD[wave][e][2][0]);
        }
        asm volatile("s_waitcnt vmcnt(0)" ::: "memory");
        float inv[TPW];
        #pragma unroll
        for (int e = 0; e < TPW; ++e) {
            float hb = stC[wave][e][lane] + b1;
            float h = silu_f(hb + stD[wave][e][0][lane])
                    + silu_f(hb + stD[wave][e][1][lane])
                    + silu_f(hb + stD[wave][e][2][lane]);
            stC[wave][e][lane] = h;
            int b = ib[e], t1 = it1[e], t2 = it2[e], t3 = it3[e];
            double pbx = pos[(size_t)b * 3], pby = pos[(size_t)b * 3 + 1], pbz = pos[(size_t)b * 3 + 2];
            double r1x = pbx - pos[(size_t)t1 * 3], r1y = pby - pos[(size_t)t1 * 3 + 1], r1z = pbz - pos[(size_t)t1 * 3 + 2];
            double r2x = pbx - pos[(size_t)t2 * 3], r2y = pby - pos[(size_t)t2 * 3 + 1], r2z = pbz - pos[(size_t)t2 * 3 + 2];
            double r3x = pbx - pos[(size_t)t3 * 3], r3y = pby - pos[(size_t)t3 * 3 + 1], r3z = pbz - pos[(size_t)t3 * 3 + 2];
            double cx = r2y * r3z - r2z * r3y;
            double cy = r2z * r3x - r2x * r3z;
            double cz = r2x * r3y - r2y * r3x;
            double stp = r1x * cx + r1y * cy + r1z * cz;
            inv[e] = (float)(1.0 / (stp + 0.01));
        }
        float acc[TPW];
        #pragma unroll
        for (int e = 0; e < TPW; ++e) acc[e] = 0.f;
        for (int k4 = 0; k4 < 64; k4 += 4) {
            float4 hk[TPW];
            #pragma unroll
            for (int e = 0; e < TPW; ++e) hk[e] = *(const float4*)&stC[wave][e][k4];
            #pragma unroll
            for (int kk = 0; kk < 4; ++kk) {
                float wk = wT[(k4 + kk) * 64 + lane];
                #pragma unroll
                for (int e = 0; e < TPW; ++e) acc[e] += (&hk[e].x)[kk] * wk;
            }
        }
        #pragma unroll
        for (int e = 0; e < TPW; ++e) {
            long t = t0 + e;
            if (t >= T) break;
            unsafeAtomicAdd(&out1[(size_t)ib[e] * DD + lane], (acc[e] + b2) * inv[e]);
        }
    }
}

extern "C" void kernel_launch(void* const* d_in, const int* in_sizes, int n_in,
                              void* d_out, int out_size, void* d_ws, size_t ws_size,
                              hipStream_t stream)
{
    const float* ns  = (const float*)d_in[0];
    const float* nc  = (const float*)d_in[1];
    const float* nv  = (const float*)d_in[2];
    const float* pos = (const float*)d_in[3];
    const int* eidx  = (const int*)d_in[4];
    const int* tidx  = (const int*)d_in[5];
    const float* Ws1 = (const float*)d_in[6];
    const float* bs1 = (const float*)d_in[7];
    const float* Ws2 = (const float*)d_in[8];
    const float* bs2 = (const float*)d_in[9];
    const float* Wc1 = (const float*)d_in[10];
    const float* bc1 = (const float*)d_in[11];
    const float* Wc2 = (const float*)d_in[12];
    const float* bc2 = (const float*)d_in[13];
    const float* WV  = (const float*)d_in[14];
    const float* bV  = (const float*)d_in[15];

    int N = in_sizes[0] / 64;
    int E = in_sizes[4] / 2;
    int T = in_sizes[5] / 4;

    float* out0 = (float*)d_out;
    float* out1 = out0 + (size_t)N * 64;
    float* out2 = out1 + (size_t)N * 64;

    float* A   = (float*)d_ws;
    float* B   = A + (size_t)N * 64;
    float* C   = B + (size_t)N * 64;
    float* Dm  = C + (size_t)N * 64;
    float* rel = Dm + (size_t)N * 64;   // E*3 floats

    rel_kernel<<<(E + 255) / 256, 256, 0, stream>>>(eidx, pos, rel, E);
    node_transform_kernel<<<2048, 256, 0, stream>>>(ns, nc, Ws1, Wc1, A, B, C, Dm, out1, N);
    node_vector_kernel<<<2048, 256, 0, stream>>>(ns, nv, WV, bV, out0, out2, N);
    edge_kernel<<<4096, 256, 0, stream>>>(A, B, nv, rel, eidx, bs1, Ws2, bs2, out0, out2, E);
    triplet_kernel<<<4096, 256, 0, stream>>>(C, Dm, pos, tidx, bc1, Wc2, bc2, out1, T);
}